// Round 19
// baseline (76.169 us; speedup 1.0000x reference)
//
#include <hip/hip_runtime.h>
#include <hip/hip_bf16.h>

#define BB 16
#define TT 2048
#define DIMC 512
#define HEADH 64

typedef __attribute__((ext_vector_type(8))) short short8v;   // 8 bf16 (4 VGPRs)
typedef __attribute__((ext_vector_type(4))) float f32x4;     // MFMA C/D

static __device__ __forceinline__ unsigned short f2bf(float f) {
    __hip_bfloat16 h = __float2bfloat16(f);          // RNE, native path
    unsigned short u;
    __builtin_memcpy(&u, &h, 2);
    return u;
}
static __device__ __forceinline__ unsigned int packbf(float lo, float hi) {
    float2 f2; f2.x = lo; f2.y = hi;
    __hip_bfloat162 h2 = __float22bfloat162_rn(f2);
    unsigned int u;
    __builtin_memcpy(&u, &h2, 4);
    return u;
}
// raw v_exp_f32 (log2 domain; args <= 0, flush-to-zero is fine for softmax)
#define EXP2R __builtin_amdgcn_exp2f
// async global->LDS, 16B per lane; LDS dest = wave-uniform base + lane*16
static __device__ __forceinline__ void async_copy16(void* lds, const void* g) {
    __builtin_amdgcn_global_load_lds(
        (const __attribute__((address_space(1))) unsigned char*)g,
        (__attribute__((address_space(3))) unsigned char*)lds, 16, 0, 0);
}

union bfrag {
    unsigned int u[4];
    short8v v;
};

// ---------------- Kernel 0: W f32 -> bf16, concat [q|k|v] rows -------------
__global__ __launch_bounds__(256) void wcvt_kernel(
    const float* __restrict__ Wq, const float* __restrict__ Wk,
    const float* __restrict__ Wv, unsigned short* __restrict__ wb)
{
    const int idx = blockIdx.x * 256 + threadIdx.x;   // 12288 threads x 8 elems
    const int e   = idx << 3;
    const int row = e >> 9, col = e & 511;
    const float* src = (row < 64) ? Wq : (row < 128) ? Wk : Wv;
    const float* p = src + (size_t)(row & 63) * DIMC + col;
    float4 a = *(const float4*)p;
    float4 b = *(const float4*)(p + 4);
    uint4 o;
    o.x = packbf(a.x, a.y); o.y = packbf(a.z, a.w);
    o.z = packbf(b.x, b.y); o.w = packbf(b.z, b.w);
    *(uint4*)(wb + e) = o;
}

// ---------------- Kernel A: MFMA QKV projection + rotary, single-barrier ----
// Round 19: t-tile 32, the ENTIRE x tile [32][512] f32 (64KB) staged up
// front (16 global_load_lds calls/wave), ONE __syncthreads, then 16 k-chunks
// of barrier-free compute (96 MFMA/wave). Rationale: r18's k-split proved
// qkv is bound by the per-iter barrier+vmcnt(0) drains (neutral at 2x waves,
// halved chain) -- so remove the drains. Bank math of [32][2048B] with
// slot^(row&7) is identical to r13's 0-conflict pattern (row stride is
// bank-aligned in both; 8 slot-groups x 8 lanes = exact b128 minimum).
// Epilogue: r12's verified t-tile-32 epilogue.
__global__ __launch_bounds__(256, 2) void qkv_mfma_kernel(
    const float* __restrict__ x,
    const unsigned short* __restrict__ wb,
    const float* __restrict__ fxr, const float* __restrict__ fxi,
    const float* __restrict__ fyr, const float* __restrict__ fyi,
    unsigned short* __restrict__ qo, unsigned short* __restrict__ ko,
    unsigned short* __restrict__ vt)
{
    __shared__ unsigned char xlds[65536];     // [32][512] f32

    const int tid = threadIdx.x;
    const int w   = tid >> 6;                 // wave -> h-tile triple
    const int l   = tid & 63;
    const int q   = l & 15;
    const int g   = l >> 4;
    const int t0  = blockIdx.x << 5;          // 32 t-rows per block

    // ---- stage whole x tile: wave w covers rows 8w..8w+7, 2 halves each ----
    #pragma unroll
    for (int c = 0; c < 16; ++c) {
        const int rc = 8 * w + (c >> 1);      // tile row
        const int hc = c & 1;                 // row half (slots 0-63 / 64-127)
        // LDS[rc][slot] = x[rc][4*(slot ^ (rc&7))]; this call: slot = 64hc + l
        const float* src = x + (size_t)(t0 + rc) * DIMC
                             + 4 * (64 * hc + (l ^ (rc & 7)));
        async_copy16(xlds + rc * 2048 + hc * 1024, src);
    }
    __syncthreads();                          // the ONLY barrier

    f32x4 acc[3][2];
    #pragma unroll
    for (int j = 0; j < 3; ++j)
        #pragma unroll
        for (int tt = 0; tt < 2; ++tt) acc[j][tt] = (f32x4){0.f, 0.f, 0.f, 0.f};

    const unsigned short* wp0 = wb + ((size_t)((3 * w + 0) * 16 + q)) * DIMC + 8 * g;
    const unsigned short* wp1 = wb + ((size_t)((3 * w + 1) * 16 + q)) * DIMC + 8 * g;
    const unsigned short* wp2 = wb + ((size_t)((3 * w + 2) * 16 + q)) * DIMC + 8 * g;

    #pragma unroll 4
    for (int kc = 0; kc < 16; ++kc) {
        const int k0 = kc << 5;
        short8v wf0 = *(const short8v*)(wp0 + k0);
        short8v wf1 = *(const short8v*)(wp1 + k0);
        short8v wf2 = *(const short8v*)(wp2 + k0);

        #pragma unroll
        for (int tt = 0; tt < 2; ++tt) {
            const int rr = tt * 16 + q;
            const int s0 = (8 * kc + 2 * g)     ^ (q & 7);  // low-3-bit XOR
            const int s1 = (8 * kc + 2 * g + 1) ^ (q & 7);
            float4 f0 = *(const float4*)(xlds + rr * 2048 + s0 * 16);
            float4 f1 = *(const float4*)(xlds + rr * 2048 + s1 * 16);
            bfrag xv;
            xv.u[0] = packbf(f0.x, f0.y); xv.u[1] = packbf(f0.z, f0.w);
            xv.u[2] = packbf(f1.x, f1.y); xv.u[3] = packbf(f1.z, f1.w);
            acc[0][tt] = __builtin_amdgcn_mfma_f32_16x16x32_bf16(wf0, xv.v, acc[0][tt], 0, 0, 0);
            acc[1][tt] = __builtin_amdgcn_mfma_f32_16x16x32_bf16(wf1, xv.v, acc[1][tt], 0, 0, 0);
            acc[2][tt] = __builtin_amdgcn_mfma_f32_16x16x32_bf16(wf2, xv.v, acc[2][tt], 0, 0, 0);
        }
    }

    // ---- epilogue (r12-verified t-tile-32 form) ----
    const float qscale = 1.4426950408889634f / 22.627416997969522f; // log2e/sqrt(512)
    #pragma unroll
    for (int j = 0; j < 3; ++j) {
        const int gt   = 3 * w + j;           // global h-tile 0..11
        const int mat  = gt >> 2;             // 0=q, 1=k, 2=v
        const int hbase = (gt & 3) * 16 + 4 * g;
        #pragma unroll
        for (int tt = 0; tt < 2; ++tt) {
            const int trow = t0 + tt * 16 + q;
            const int tl   = trow & (TT - 1);
            if (mat == 2) {
                const int b = trow >> 11;
                #pragma unroll
                for (int r = 0; r < 4; ++r)
                    vt[((size_t)(b * HEADH) + hbase + r) * TT + tl] = f2bf(acc[j][tt][r]);
            } else {
                const float sc = (mat == 0) ? qscale : 1.f;
                unsigned short* dst = ((mat == 0) ? qo : ko) + (size_t)trow * HEADH;
                const int half = hbase >> 5;
                const float* frt = half ? fyr : fxr;
                const float* fit = half ? fyi : fxi;
                const int pi0 = (hbase & 31) >> 1;
                float fr0 = frt[tl * 16 + pi0],     fi0 = fit[tl * 16 + pi0];
                float fr1 = frt[tl * 16 + pi0 + 1], fi1 = fit[tl * 16 + pi0 + 1];
                float e0 = acc[j][tt][0] * fr0 - acc[j][tt][1] * fi0;
                float e1 = acc[j][tt][0] * fi0 + acc[j][tt][1] * fr0;
                float e2 = acc[j][tt][2] * fr1 - acc[j][tt][3] * fi1;
                float e3 = acc[j][tt][2] * fi1 + acc[j][tt][3] * fr1;
                uint2 ow;
                ow.x = packbf(e0 * sc, e1 * sc);
                ow.y = packbf(e2 * sc, e3 * sc);
                *(uint2*)(dst + hbase) = ow;
            }
        }
    }
}

// ---------------- Kernel B: MFMA flash attention, 16-wave q-tile-128 --------
// (unchanged from round 17)
__global__ __launch_bounds__(1024, 4) void attn_mfma_kernel(
    const unsigned short* __restrict__ qws,   // [b][t][64] bf16, pre-scaled
    const unsigned short* __restrict__ kws,   // [b][t][64] bf16
    const unsigned short* __restrict__ vtw,   // [b][d][t]  bf16 (V^T)
    float* __restrict__ out)
{
    __shared__ unsigned char smem[98304];

    const int tid = threadIdx.x;
    const int w   = tid >> 6;                 // 0..15
    const int wq  = w & 7;                    // q-subtile
    const int h   = w >> 3;                   // kv half
    const int l   = tid & 63;
    const int q   = l & 15;
    const int g   = l >> 4;
    const int b   = blockIdx.x >> 4;
    const int q0  = (blockIdx.x & 15) << 7;   // 128 q-rows per block
    const int qw  = q0 + 16 * wq;             // this wave's q base
    const int rx  = q & 7;                    // read-side swizzle
    const int swz = (q & 7) << 2;             // plds swizzle (verified r2-r18)

    const int rl = l >> 3;
    const int sl = (l & 7) ^ rl;              // involution pre-swizzle

    unsigned int* pldsw = (unsigned int*)(smem + 65536 + (w << 11));

    const unsigned short* kbase = kws + (size_t)b * TT * HEADH;
    const unsigned short* vbase = vtw + (size_t)b * HEADH * TT;

    const unsigned short* ksrc = kbase + (size_t)(h * 1024 + 8 * wq + rl) * HEADH + 8 * sl;
    const unsigned short* vsrc = vbase + (size_t)(8 * wq + rl) * TT + h * 1024 + 8 * sl;

#define STAGE_TILE(bufsel, kv)  do {                                          \
        unsigned char* kd = smem + (h << 14) + (bufsel) * 8192 + (wq << 10);  \
        async_copy16(kd, ksrc + (size_t)(kv) * HEADH);                        \
        unsigned char* vd = smem + 32768 + (h << 14) + (bufsel) * 8192 + (wq << 10); \
        async_copy16(vd, vsrc + (kv));                                        \
    } while (0)

    short8v qf0, qf1;
    {
        const unsigned short* qp = qws + ((size_t)(b * TT + qw + q)) * HEADH + 8 * g;
        qf0 = *(const short8v*)(qp);
        qf1 = *(const short8v*)(qp + 32);
    }

    f32x4 oacc[4];
    #pragma unroll
    for (int mt = 0; mt < 4; ++mt) oacc[mt] = (f32x4){0.f, 0.f, 0.f, 0.f};
    float m = -1e30f, lsum = 0.f;

    STAGE_TILE(0, 0);
    __syncthreads();                          // tile 0 resident

    int cur = 0;
    for (int it = 0; it < 16; ++it) {
        const int kv0 = it << 6;              // offset within this half
        if (it < 15) STAGE_TILE(cur ^ 1, kv0 + 64);

        const unsigned char* kb = smem + (h << 14) + cur * 8192;
        const unsigned char* vb = smem + 32768 + (h << 14) + cur * 8192;

        // ---- QK^T from LDS ----
        f32x4 sacc[4];
        #pragma unroll
        for (int n = 0; n < 4; ++n) {
            const int r = 16 * n + q;
            const short8v k0 = *(const short8v*)(kb + r * 128 + ((g ^ rx) << 4));
            const short8v k1 = *(const short8v*)(kb + r * 128 + (((4 + g) ^ rx) << 4));
            f32x4 z = (f32x4){0.f, 0.f, 0.f, 0.f};
            z = __builtin_amdgcn_mfma_f32_16x16x32_bf16(k0, qf0, z, 0, 0, 0);
            z = __builtin_amdgcn_mfma_f32_16x16x32_bf16(k1, qf1, z, 0, 0, 0);
            sacc[n] = z;
        }

        // ---- online softmax (lane owns q-row qw + (l&15)) ----
        float nx[4];
        #pragma unroll
        for (int n = 0; n < 4; ++n)
            nx[n] = fmaxf(fmaxf(sacc[n][0], sacc[n][1]),
                          fmaxf(sacc[n][2], sacc[n][3]));
        float cmax = fmaxf(fmaxf(nx[0], nx[1]), fmaxf(nx[2], nx[3]));
        cmax = fmaxf(cmax, __shfl_xor(cmax, 16));
        cmax = fmaxf(cmax, __shfl_xor(cmax, 32));
        const float mnew = fmaxf(m, cmax);

        float p[4][4];
        #pragma unroll
        for (int n = 0; n < 4; ++n) {
            #pragma unroll
            for (int r = 0; r < 4; ++r)
                p[n][r] = EXP2R(sacc[n][r] - mnew);   // raw v_exp_f32
            uint2 wv;
            wv.x = packbf(p[n][0], p[n][1]);
            wv.y = packbf(p[n][2], p[n][3]);
            *(uint2*)&pldsw[q * 32 + ((8 * n + 2 * g) ^ swz)] = wv;
        }

        const float sc = EXP2R(m - mnew);
        if (__any(cmax > m)) {
            #pragma unroll
            for (int mt = 0; mt < 4; ++mt)
                #pragma unroll
                for (int r = 0; r < 4; ++r) oacc[mt][r] *= sc;
        }

        // ---- PV: out^T += V^T . P^T ----
        #pragma unroll
        for (int s = 0; s < 2; ++s) {
            const short8v pb = *(const short8v*)&pldsw[q * 32 + ((16 * s + 4 * g) ^ swz)];
            #pragma unroll
            for (int mt = 0; mt < 4; ++mt) {
                const int d = 16 * mt + q;
                const short8v vfr = *(const short8v*)(vb + d * 128 + ((((s << 2) + g) ^ rx) << 4));
                oacc[mt] = __builtin_amdgcn_mfma_f32_16x16x32_bf16(vfr, pb, oacc[mt], 0, 0, 0);
            }
        }

        // ---- psum reduce off the critical path ----
        float psum = 0.f;
        #pragma unroll
        for (int n = 0; n < 4; ++n)
            #pragma unroll
            for (int r = 0; r < 4; ++r) psum += p[n][r];
        psum += __shfl_xor(psum, 16);
        psum += __shfl_xor(psum, 32);
        lsum = lsum * sc + psum;
        m = mnew;

        __syncthreads();                      // nxt resident; cur reads done
        cur ^= 1;
    }

    // ---- 2-way combine of KV-half partials through LDS ----
    __syncthreads();                           // all staging/plds reads done
    float* o_f  = (float*)smem;                // [2][128][64] f32 = 64KB
    float* ml_f = (float*)(smem + 65536);      // [2][2][128]
    {
        const int prow = h * 128 + 16 * wq + q;
        #pragma unroll
        for (int mt = 0; mt < 4; ++mt)
            *(f32x4*)&o_f[prow * 64 + 16 * mt + 4 * g] = oacc[mt];
        if (g == 0) {
            ml_f[h * 256 + 16 * wq + q]       = m;
            ml_f[h * 256 + 128 + 16 * wq + q] = lsum;
        }
    }
    __syncthreads();

    const int cq = tid >> 3;                   // 0..127: q row
    const int ch = (tid & 7) << 3;             // 0..56: h group of 8
    const float m0 = ml_f[cq],       l0 = ml_f[128 + cq];
    const float m1 = ml_f[256 + cq], l1 = ml_f[384 + cq];
    const float M  = fmaxf(m0, m1);
    const float a0 = EXP2R(m0 - M), a1 = EXP2R(m1 - M);
    const float inv = 1.f / (a0 * l0 + a1 * l1);
    const float* o0 = &o_f[cq * 64 + ch];
    const float* o1 = &o_f[(128 + cq) * 64 + ch];
    float4 A0 = *(const float4*)(o0), B0 = *(const float4*)(o0 + 4);
    float4 A1 = *(const float4*)(o1), B1 = *(const float4*)(o1 + 4);
    float* op = out + ((size_t)(b * TT + q0 + cq)) * HEADH + ch;
    *(float4*)(op)     = make_float4((a0 * A0.x + a1 * A1.x) * inv,
                                     (a0 * A0.y + a1 * A1.y) * inv,
                                     (a0 * A0.z + a1 * A1.z) * inv,
                                     (a0 * A0.w + a1 * A1.w) * inv);
    *(float4*)(op + 4) = make_float4((a0 * B0.x + a1 * B1.x) * inv,
                                     (a0 * B0.y + a1 * B1.y) * inv,
                                     (a0 * B0.z + a1 * B1.z) * inv,
                                     (a0 * B0.w + a1 * B1.w) * inv);
#undef STAGE_TILE
}

extern "C" void kernel_launch(void* const* d_in, const int* in_sizes, int n_in,
                              void* d_out, int out_size, void* d_ws, size_t ws_size,
                              hipStream_t stream)
{
    const float* x   = (const float*)d_in[0];
    const float* Wq  = (const float*)d_in[1];
    const float* Wk  = (const float*)d_in[2];
    const float* Wv  = (const float*)d_in[3];
    const float* fxr = (const float*)d_in[4];
    const float* fxi = (const float*)d_in[5];
    const float* fyr = (const float*)d_in[6];
    const float* fyi = (const float*)d_in[7];
    float* out = (float*)d_out;

    unsigned short* qo = (unsigned short*)d_ws;                  // 4 MB
    unsigned short* ko = qo + (size_t)BB * TT * HEADH;           // 4 MB
    unsigned short* vt = ko + (size_t)BB * TT * HEADH;           // 4 MB
    unsigned short* wb = vt + (size_t)BB * TT * HEADH;           // 192 KB

    wcvt_kernel<<<48, 256, 0, stream>>>(Wq, Wk, Wv, wb);
    qkv_mfma_kernel<<<(BB * TT) / 32, 256, 0, stream>>>(x, wb, fxr, fxi, fyr, fyi,
                                                        qo, ko, vt);
    attn_mfma_kernel<<<BB * 16, 1024, 0, stream>>>(qo, ko, vt, out);
}

// Round 20
// 66.047 us; speedup vs baseline: 1.1532x; 1.1532x over previous
//
#include <hip/hip_runtime.h>
#include <hip/hip_bf16.h>

#define BB 16
#define TT 2048
#define DIMC 512
#define HEADH 64

typedef __attribute__((ext_vector_type(8))) short short8v;   // 8 bf16 (4 VGPRs)
typedef __attribute__((ext_vector_type(4))) float f32x4;     // MFMA C/D

static __device__ __forceinline__ unsigned short f2bf(float f) {
    __hip_bfloat16 h = __float2bfloat16(f);          // RNE, native path
    unsigned short u;
    __builtin_memcpy(&u, &h, 2);
    return u;
}
static __device__ __forceinline__ unsigned int packbf(float lo, float hi) {
    float2 f2; f2.x = lo; f2.y = hi;
    __hip_bfloat162 h2 = __float22bfloat162_rn(f2);
    unsigned int u;
    __builtin_memcpy(&u, &h2, 4);
    return u;
}
// raw v_exp_f32 (log2 domain; args <= 0, flush-to-zero is fine for softmax)
#define EXP2R __builtin_amdgcn_exp2f
// async global->LDS, 16B per lane; LDS dest = wave-uniform base + lane*16
static __device__ __forceinline__ void async_copy16(void* lds, const void* g) {
    __builtin_amdgcn_global_load_lds(
        (const __attribute__((address_space(1))) unsigned char*)g,
        (__attribute__((address_space(3))) unsigned char*)lds, 16, 0, 0);
}

union bfrag {
    unsigned int u[4];
    short8v v;
};

// ---------------- Kernel 0: W f32 -> bf16, concat [q|k|v] rows -------------
__global__ __launch_bounds__(256) void wcvt_kernel(
    const float* __restrict__ Wq, const float* __restrict__ Wk,
    const float* __restrict__ Wv, unsigned short* __restrict__ wb)
{
    const int idx = blockIdx.x * 256 + threadIdx.x;   // 12288 threads x 8 elems
    const int e   = idx << 3;
    const int row = e >> 9, col = e & 511;
    const float* src = (row < 64) ? Wq : (row < 128) ? Wk : Wv;
    const float* p = src + (size_t)(row & 63) * DIMC + col;
    float4 a = *(const float4*)p;
    float4 b = *(const float4*)(p + 4);
    uint4 o;
    o.x = packbf(a.x, a.y); o.y = packbf(a.z, a.w);
    o.z = packbf(b.x, b.y); o.w = packbf(b.z, b.w);
    *(uint4*)(wb + e) = o;
}

// ---------------- Kernel A: MFMA QKV projection + rotary, counted-vmcnt -----
// Round 20: r13's exact tiling and data maps (t-tile 64, K-chunk 32, 16
// iters, 4 waves, 2 staging calls/wave/iter), but the per-iter full
// __syncthreads vmcnt(0) drain (diagnosed via r18/r19 as the binding cost:
// it waits on the JUST-issued next-tile stage, ~600cy exposed x 16 iters)
// is replaced by the T4 pattern: triple-buffered staging + counted
// s_waitcnt vmcnt(2) + raw s_barrier. Buf i's loads are issued at iter i-2
// (after that barrier) -> ~2 iterations of flight before use.
// Correctness: each wave waits ITS OWN buf-i calls (vmcnt(2): leaves only
// the 2 newer buf-i+1 calls in flight) BEFORE the barrier; after the
// barrier all waves' buf-i loads are complete. WAR: buf (i+2)%3 was last
// read at iter i-1, whose reads all complete before the iter-i barrier.
__global__ __launch_bounds__(256, 2) void qkv_mfma_kernel(
    const float* __restrict__ x,
    const unsigned short* __restrict__ wb,
    const float* __restrict__ fxr, const float* __restrict__ fxi,
    const float* __restrict__ fyr, const float* __restrict__ fyi,
    unsigned short* __restrict__ qo, unsigned short* __restrict__ ko,
    unsigned short* __restrict__ vt)
{
    __shared__ unsigned char xlds[24576];     // 3 bufs x [64][32] f32 (8KB)

    const int tid = threadIdx.x;
    const int w   = tid >> 6;                 // wave -> h-tile triple
    const int l   = tid & 63;
    const int q   = l & 15;
    const int g   = l >> 4;
    const int t0  = blockIdx.x << 6;          // 64 t-rows per block

    f32x4 acc[3][4];
    #pragma unroll
    for (int j = 0; j < 3; ++j)
        #pragma unroll
        for (int tt = 0; tt < 4; ++tt) acc[j][tt] = (f32x4){0.f, 0.f, 0.f, 0.f};

    const unsigned short* wp0 = wb + ((size_t)((3 * w + 0) * 16 + q)) * DIMC + 8 * g;
    const unsigned short* wp1 = wb + ((size_t)((3 * w + 1) * 16 + q)) * DIMC + 8 * g;
    const unsigned short* wp2 = wb + ((size_t)((3 * w + 2) * 16 + q)) * DIMC + 8 * g;

    const int rl = l >> 3;                    // 0..7 row-in-call
    const int cb = (l & 7) ^ rl;              // source col-block (involution)
    const float* xsrc0 = x + (size_t)(t0 + 16 * w + 0 + rl) * DIMC + 4 * cb;
    const float* xsrc1 = x + (size_t)(t0 + 16 * w + 8 + rl) * DIMC + 4 * cb;
    unsigned char* xdst0 = xlds + (16 * w + 0) * 128;   // wave-uniform bases
    unsigned char* xdst1 = xlds + (16 * w + 8) * 128;

#define STAGE_X(buf, k0) do {                                                 \
        async_copy16(xdst0 + (buf) * 8192, xsrc0 + (k0));                     \
        async_copy16(xdst1 + (buf) * 8192, xsrc1 + (k0));                     \
    } while (0)

    STAGE_X(0, 0);                            // prologue: 2 tiles in flight
    STAGE_X(1, 32);

    #pragma unroll
    for (int it = 0; it < 16; ++it) {
        // own buf-it calls complete; newer calls stay in flight
        if (it < 15) asm volatile("s_waitcnt vmcnt(2)" ::: "memory");
        else         asm volatile("s_waitcnt vmcnt(0)" ::: "memory");
        __builtin_amdgcn_s_barrier();         // raw: no vmcnt(0) drain
        if (it + 2 < 16) STAGE_X((it + 2) % 3, (it + 2) << 5);

        const int k0 = it << 5;
        short8v wf0 = *(const short8v*)(wp0 + k0);
        short8v wf1 = *(const short8v*)(wp1 + k0);
        short8v wf2 = *(const short8v*)(wp2 + k0);

        const unsigned char* xb = xlds + (it % 3) * 8192;
        #pragma unroll
        for (int tt = 0; tt < 4; ++tt) {
            const int rr = tt * 16 + q;
            const int s0 = (2 * g)     ^ (q & 7);
            const int s1 = (2 * g + 1) ^ (q & 7);
            float4 f0 = *(const float4*)(xb + rr * 128 + s0 * 16);
            float4 f1 = *(const float4*)(xb + rr * 128 + s1 * 16);
            bfrag xv;
            xv.u[0] = packbf(f0.x, f0.y); xv.u[1] = packbf(f0.z, f0.w);
            xv.u[2] = packbf(f1.x, f1.y); xv.u[3] = packbf(f1.z, f1.w);
            acc[0][tt] = __builtin_amdgcn_mfma_f32_16x16x32_bf16(wf0, xv.v, acc[0][tt], 0, 0, 0);
            acc[1][tt] = __builtin_amdgcn_mfma_f32_16x16x32_bf16(wf1, xv.v, acc[1][tt], 0, 0, 0);
            acc[2][tt] = __builtin_amdgcn_mfma_f32_16x16x32_bf16(wf2, xv.v, acc[2][tt], 0, 0, 0);
        }
    }

    // ---- epilogue (r13-verbatim) ----
    const float qscale = 1.4426950408889634f / 22.627416997969522f; // log2e/sqrt(512)
    #pragma unroll
    for (int j = 0; j < 3; ++j) {
        const int gt   = 3 * w + j;           // global h-tile 0..11
        const int mat  = gt >> 2;             // 0=q, 1=k, 2=v
        const int hbase = (gt & 3) * 16 + 4 * g;
        #pragma unroll
        for (int tt = 0; tt < 4; ++tt) {
            const int trow = t0 + tt * 16 + q;
            const int tl   = trow & (TT - 1);
            if (mat == 2) {
                const int b = trow >> 11;
                #pragma unroll
                for (int r = 0; r < 4; ++r)
                    vt[((size_t)(b * HEADH) + hbase + r) * TT + tl] = f2bf(acc[j][tt][r]);
            } else {
                const float sc = (mat == 0) ? qscale : 1.f;
                unsigned short* dst = ((mat == 0) ? qo : ko) + (size_t)trow * HEADH;
                const int half = hbase >> 5;
                const float* frt = half ? fyr : fxr;
                const float* fit = half ? fyi : fxi;
                const int pi0 = (hbase & 31) >> 1;
                float fr0 = frt[tl * 16 + pi0],     fi0 = fit[tl * 16 + pi0];
                float fr1 = frt[tl * 16 + pi0 + 1], fi1 = fit[tl * 16 + pi0 + 1];
                float e0 = acc[j][tt][0] * fr0 - acc[j][tt][1] * fi0;
                float e1 = acc[j][tt][0] * fi0 + acc[j][tt][1] * fr0;
                float e2 = acc[j][tt][2] * fr1 - acc[j][tt][3] * fi1;
                float e3 = acc[j][tt][2] * fi1 + acc[j][tt][3] * fr1;
                uint2 ow;
                ow.x = packbf(e0 * sc, e1 * sc);
                ow.y = packbf(e2 * sc, e3 * sc);
                *(uint2*)(dst + hbase) = ow;
            }
        }
    }
#undef STAGE_X
}

// ---------------- Kernel B: MFMA flash attention, 16-wave q-tile-128 --------
// (unchanged from round 17: best measured attn, ~37us)
__global__ __launch_bounds__(1024, 4) void attn_mfma_kernel(
    const unsigned short* __restrict__ qws,   // [b][t][64] bf16, pre-scaled
    const unsigned short* __restrict__ kws,   // [b][t][64] bf16
    const unsigned short* __restrict__ vtw,   // [b][d][t]  bf16 (V^T)
    float* __restrict__ out)
{
    __shared__ unsigned char smem[98304];

    const int tid = threadIdx.x;
    const int w   = tid >> 6;                 // 0..15
    const int wq  = w & 7;                    // q-subtile
    const int h   = w >> 3;                   // kv half
    const int l   = tid & 63;
    const int q   = l & 15;
    const int g   = l >> 4;
    const int b   = blockIdx.x >> 4;
    const int q0  = (blockIdx.x & 15) << 7;   // 128 q-rows per block
    const int qw  = q0 + 16 * wq;             // this wave's q base
    const int rx  = q & 7;                    // read-side swizzle
    const int swz = (q & 7) << 2;             // plds swizzle (verified r2-r18)

    const int rl = l >> 3;
    const int sl = (l & 7) ^ rl;              // involution pre-swizzle

    unsigned int* pldsw = (unsigned int*)(smem + 65536 + (w << 11));

    const unsigned short* kbase = kws + (size_t)b * TT * HEADH;
    const unsigned short* vbase = vtw + (size_t)b * HEADH * TT;

    const unsigned short* ksrc = kbase + (size_t)(h * 1024 + 8 * wq + rl) * HEADH + 8 * sl;
    const unsigned short* vsrc = vbase + (size_t)(8 * wq + rl) * TT + h * 1024 + 8 * sl;

#define STAGE_TILE(bufsel, kv)  do {                                          \
        unsigned char* kd = smem + (h << 14) + (bufsel) * 8192 + (wq << 10);  \
        async_copy16(kd, ksrc + (size_t)(kv) * HEADH);                        \
        unsigned char* vd = smem + 32768 + (h << 14) + (bufsel) * 8192 + (wq << 10); \
        async_copy16(vd, vsrc + (kv));                                        \
    } while (0)

    short8v qf0, qf1;
    {
        const unsigned short* qp = qws + ((size_t)(b * TT + qw + q)) * HEADH + 8 * g;
        qf0 = *(const short8v*)(qp);
        qf1 = *(const short8v*)(qp + 32);
    }

    f32x4 oacc[4];
    #pragma unroll
    for (int mt = 0; mt < 4; ++mt) oacc[mt] = (f32x4){0.f, 0.f, 0.f, 0.f};
    float m = -1e30f, lsum = 0.f;

    STAGE_TILE(0, 0);
    __syncthreads();                          // tile 0 resident

    int cur = 0;
    for (int it = 0; it < 16; ++it) {
        const int kv0 = it << 6;              // offset within this half
        if (it < 15) STAGE_TILE(cur ^ 1, kv0 + 64);

        const unsigned char* kb = smem + (h << 14) + cur * 8192;
        const unsigned char* vb = smem + 32768 + (h << 14) + cur * 8192;

        // ---- QK^T from LDS ----
        f32x4 sacc[4];
        #pragma unroll
        for (int n = 0; n < 4; ++n) {
            const int r = 16 * n + q;
            const short8v k0 = *(const short8v*)(kb + r * 128 + ((g ^ rx) << 4));
            const short8v k1 = *(const short8v*)(kb + r * 128 + (((4 + g) ^ rx) << 4));
            f32x4 z = (f32x4){0.f, 0.f, 0.f, 0.f};
            z = __builtin_amdgcn_mfma_f32_16x16x32_bf16(k0, qf0, z, 0, 0, 0);
            z = __builtin_amdgcn_mfma_f32_16x16x32_bf16(k1, qf1, z, 0, 0, 0);
            sacc[n] = z;
        }

        // ---- online softmax (lane owns q-row qw + (l&15)) ----
        float nx[4];
        #pragma unroll
        for (int n = 0; n < 4; ++n)
            nx[n] = fmaxf(fmaxf(sacc[n][0], sacc[n][1]),
                          fmaxf(sacc[n][2], sacc[n][3]));
        float cmax = fmaxf(fmaxf(nx[0], nx[1]), fmaxf(nx[2], nx[3]));
        cmax = fmaxf(cmax, __shfl_xor(cmax, 16));
        cmax = fmaxf(cmax, __shfl_xor(cmax, 32));
        const float mnew = fmaxf(m, cmax);

        float p[4][4];
        #pragma unroll
        for (int n = 0; n < 4; ++n) {
            #pragma unroll
            for (int r = 0; r < 4; ++r)
                p[n][r] = EXP2R(sacc[n][r] - mnew);   // raw v_exp_f32
            uint2 wv;
            wv.x = packbf(p[n][0], p[n][1]);
            wv.y = packbf(p[n][2], p[n][3]);
            *(uint2*)&pldsw[q * 32 + ((8 * n + 2 * g) ^ swz)] = wv;
        }

        const float sc = EXP2R(m - mnew);
        if (__any(cmax > m)) {
            #pragma unroll
            for (int mt = 0; mt < 4; ++mt)
                #pragma unroll
                for (int r = 0; r < 4; ++r) oacc[mt][r] *= sc;
        }

        // ---- PV: out^T += V^T . P^T ----
        #pragma unroll
        for (int s = 0; s < 2; ++s) {
            const short8v pb = *(const short8v*)&pldsw[q * 32 + ((16 * s + 4 * g) ^ swz)];
            #pragma unroll
            for (int mt = 0; mt < 4; ++mt) {
                const int d = 16 * mt + q;
                const short8v vfr = *(const short8v*)(vb + d * 128 + ((((s << 2) + g) ^ rx) << 4));
                oacc[mt] = __builtin_amdgcn_mfma_f32_16x16x32_bf16(vfr, pb, oacc[mt], 0, 0, 0);
            }
        }

        // ---- psum reduce off the critical path ----
        float psum = 0.f;
        #pragma unroll
        for (int n = 0; n < 4; ++n)
            #pragma unroll
            for (int r = 0; r < 4; ++r) psum += p[n][r];
        psum += __shfl_xor(psum, 16);
        psum += __shfl_xor(psum, 32);
        lsum = lsum * sc + psum;
        m = mnew;

        __syncthreads();                      // nxt resident; cur reads done
        cur ^= 1;
    }

    // ---- 2-way combine of KV-half partials through LDS ----
    __syncthreads();                           // all staging/plds reads done
    float* o_f  = (float*)smem;                // [2][128][64] f32 = 64KB
    float* ml_f = (float*)(smem + 65536);      // [2][2][128]
    {
        const int prow = h * 128 + 16 * wq + q;
        #pragma unroll
        for (int mt = 0; mt < 4; ++mt)
            *(f32x4*)&o_f[prow * 64 + 16 * mt + 4 * g] = oacc[mt];
        if (g == 0) {
            ml_f[h * 256 + 16 * wq + q]       = m;
            ml_f[h * 256 + 128 + 16 * wq + q] = lsum;
        }
    }
    __syncthreads();

    const int cq = tid >> 3;                   // 0..127: q row
    const int ch = (tid & 7) << 3;             // 0..56: h group of 8
    const float m0 = ml_f[cq],       l0 = ml_f[128 + cq];
    const float m1 = ml_f[256 + cq], l1 = ml_f[384 + cq];
    const float M  = fmaxf(m0, m1);
    const float a0 = EXP2R(m0 - M), a1 = EXP2R(m1 - M);
    const float inv = 1.f / (a0 * l0 + a1 * l1);
    const float* o0 = &o_f[cq * 64 + ch];
    const float* o1 = &o_f[(128 + cq) * 64 + ch];
    float4 A0 = *(const float4*)(o0), B0 = *(const float4*)(o0 + 4);
    float4 A1 = *(const float4*)(o1), B1 = *(const float4*)(o1 + 4);
    float* op = out + ((size_t)(b * TT + q0 + cq)) * HEADH + ch;
    *(float4*)(op)     = make_float4((a0 * A0.x + a1 * A1.x) * inv,
                                     (a0 * A0.y + a1 * A1.y) * inv,
                                     (a0 * A0.z + a1 * A1.z) * inv,
                                     (a0 * A0.w + a1 * A1.w) * inv);
    *(float4*)(op + 4) = make_float4((a0 * B0.x + a1 * B1.x) * inv,
                                     (a0 * B0.y + a1 * B1.y) * inv,
                                     (a0 * B0.z + a1 * B1.z) * inv,
                                     (a0 * B0.w + a1 * B1.w) * inv);
#undef STAGE_TILE
}

extern "C" void kernel_launch(void* const* d_in, const int* in_sizes, int n_in,
                              void* d_out, int out_size, void* d_ws, size_t ws_size,
                              hipStream_t stream)
{
    const float* x   = (const float*)d_in[0];
    const float* Wq  = (const float*)d_in[1];
    const float* Wk  = (const float*)d_in[2];
    const float* Wv  = (const float*)d_in[3];
    const float* fxr = (const float*)d_in[4];
    const float* fxi = (const float*)d_in[5];
    const float* fyr = (const float*)d_in[6];
    const float* fyi = (const float*)d_in[7];
    float* out = (float*)d_out;

    unsigned short* qo = (unsigned short*)d_ws;                  // 4 MB
    unsigned short* ko = qo + (size_t)BB * TT * HEADH;           // 4 MB
    unsigned short* vt = ko + (size_t)BB * TT * HEADH;           // 4 MB
    unsigned short* wb = vt + (size_t)BB * TT * HEADH;           // 192 KB

    wcvt_kernel<<<48, 256, 0, stream>>>(Wq, Wk, Wv, wb);
    qkv_mfma_kernel<<<(BB * TT) / 64, 256, 0, stream>>>(x, wb, fxr, fxi, fyr, fyi,
                                                        qo, ko, vt);
    attn_mfma_kernel<<<BB * 16, 1024, 0, stream>>>(qo, ko, vt, out);
}

// Round 21
// 65.220 us; speedup vs baseline: 1.1679x; 1.0127x over previous
//
#include <hip/hip_runtime.h>
#include <hip/hip_bf16.h>

#define BB 16
#define TT 2048
#define DIMC 512
#define HEADH 64

typedef __attribute__((ext_vector_type(8))) short short8v;   // 8 bf16 (4 VGPRs)
typedef __attribute__((ext_vector_type(4))) float f32x4;     // MFMA C/D

static __device__ __forceinline__ unsigned short f2bf(float f) {
    __hip_bfloat16 h = __float2bfloat16(f);          // RNE, native path
    unsigned short u;
    __builtin_memcpy(&u, &h, 2);
    return u;
}
static __device__ __forceinline__ unsigned int packbf(float lo, float hi) {
    float2 f2; f2.x = lo; f2.y = hi;
    __hip_bfloat162 h2 = __float22bfloat162_rn(f2);
    unsigned int u;
    __builtin_memcpy(&u, &h2, 4);
    return u;
}
// raw v_exp_f32 (log2 domain; args <= 0, flush-to-zero is fine for softmax)
#define EXP2R __builtin_amdgcn_exp2f
// async global->LDS, 16B per lane; LDS dest = wave-uniform base + lane*16
static __device__ __forceinline__ void async_copy16(void* lds, const void* g) {
    __builtin_amdgcn_global_load_lds(
        (const __attribute__((address_space(1))) unsigned char*)g,
        (__attribute__((address_space(3))) unsigned char*)lds, 16, 0, 0);
}

union bfrag {
    unsigned int u[4];
    short8v v;
};

// ---------------- Kernel 0: W f32 -> bf16, concat [q|k|v] rows -------------
__global__ __launch_bounds__(256) void wcvt_kernel(
    const float* __restrict__ Wq, const float* __restrict__ Wk,
    const float* __restrict__ Wv, unsigned short* __restrict__ wb)
{
    const int idx = blockIdx.x * 256 + threadIdx.x;   // 12288 threads x 8 elems
    const int e   = idx << 3;
    const int row = e >> 9, col = e & 511;
    const float* src = (row < 64) ? Wq : (row < 128) ? Wk : Wv;
    const float* p = src + (size_t)(row & 63) * DIMC + col;
    float4 a = *(const float4*)p;
    float4 b = *(const float4*)(p + 4);
    uint4 o;
    o.x = packbf(a.x, a.y); o.y = packbf(a.z, a.w);
    o.z = packbf(b.x, b.y); o.w = packbf(b.z, b.w);
    *(uint4*)(wb + e) = o;
}

// ---------------- Kernel A: MFMA QKV projection + rotary, LDS-staged --------
// (exact r13 version: measured ~24us; r18/r19/r20 proved this is the best
// measured point for this kernel shape -- four orthogonal levers all null)
__global__ __launch_bounds__(256, 2) void qkv_mfma_kernel(
    const float* __restrict__ x,
    const unsigned short* __restrict__ wb,
    const float* __restrict__ fxr, const float* __restrict__ fxi,
    const float* __restrict__ fyr, const float* __restrict__ fyi,
    unsigned short* __restrict__ qo, unsigned short* __restrict__ ko,
    unsigned short* __restrict__ vt)
{
    __shared__ unsigned char xlds[16384];     // [2][64][32] f32, dbuf

    const int tid = threadIdx.x;
    const int w   = tid >> 6;                 // wave -> h-tile triple
    const int l   = tid & 63;
    const int q   = l & 15;
    const int g   = l >> 4;
    const int t0  = blockIdx.x << 6;          // 64 t-rows per block

    f32x4 acc[3][4];
    #pragma unroll
    for (int j = 0; j < 3; ++j)
        #pragma unroll
        for (int tt = 0; tt < 4; ++tt) acc[j][tt] = (f32x4){0.f, 0.f, 0.f, 0.f};

    const unsigned short* wp0 = wb + ((size_t)((3 * w + 0) * 16 + q)) * DIMC + 8 * g;
    const unsigned short* wp1 = wb + ((size_t)((3 * w + 1) * 16 + q)) * DIMC + 8 * g;
    const unsigned short* wp2 = wb + ((size_t)((3 * w + 2) * 16 + q)) * DIMC + 8 * g;

    const int rl = l >> 3;                    // 0..7 row-in-call
    const int cb = (l & 7) ^ rl;              // source col-block (involution)
    const float* xsrc0 = x + (size_t)(t0 + 16 * w + 0 + rl) * DIMC + 4 * cb;
    const float* xsrc1 = x + (size_t)(t0 + 16 * w + 8 + rl) * DIMC + 4 * cb;
    unsigned char* xdst0 = xlds + (16 * w + 0) * 128;   // wave-uniform bases
    unsigned char* xdst1 = xlds + (16 * w + 8) * 128;

#define STAGE_X(bufsel, k0) do {                                              \
        async_copy16(xdst0 + (bufsel) * 8192, xsrc0 + (k0));                  \
        async_copy16(xdst1 + (bufsel) * 8192, xsrc1 + (k0));                  \
    } while (0)

    STAGE_X(0, 0);
    __syncthreads();

    int cur = 0;
    for (int it = 0; it < 16; ++it) {
        const int k0 = it << 5;
        if (it < 15) STAGE_X(cur ^ 1, k0 + 32);

        short8v wf0 = *(const short8v*)(wp0 + k0);
        short8v wf1 = *(const short8v*)(wp1 + k0);
        short8v wf2 = *(const short8v*)(wp2 + k0);

        const unsigned char* xb = xlds + cur * 8192;
        #pragma unroll
        for (int tt = 0; tt < 4; ++tt) {
            const int rr = tt * 16 + q;
            const int s0 = (2 * g)     ^ (q & 7);
            const int s1 = (2 * g + 1) ^ (q & 7);
            float4 f0 = *(const float4*)(xb + rr * 128 + s0 * 16);
            float4 f1 = *(const float4*)(xb + rr * 128 + s1 * 16);
            bfrag xv;
            xv.u[0] = packbf(f0.x, f0.y); xv.u[1] = packbf(f0.z, f0.w);
            xv.u[2] = packbf(f1.x, f1.y); xv.u[3] = packbf(f1.z, f1.w);
            acc[0][tt] = __builtin_amdgcn_mfma_f32_16x16x32_bf16(wf0, xv.v, acc[0][tt], 0, 0, 0);
            acc[1][tt] = __builtin_amdgcn_mfma_f32_16x16x32_bf16(wf1, xv.v, acc[1][tt], 0, 0, 0);
            acc[2][tt] = __builtin_amdgcn_mfma_f32_16x16x32_bf16(wf2, xv.v, acc[2][tt], 0, 0, 0);
        }

        __syncthreads();                      // nxt resident; cur reads done
        cur ^= 1;
    }

    const float qscale = 1.4426950408889634f / 22.627416997969522f; // log2e/sqrt(512)
    #pragma unroll
    for (int j = 0; j < 3; ++j) {
        const int gt   = 3 * w + j;           // global h-tile 0..11
        const int mat  = gt >> 2;             // 0=q, 1=k, 2=v
        const int hbase = (gt & 3) * 16 + 4 * g;
        #pragma unroll
        for (int tt = 0; tt < 4; ++tt) {
            const int trow = t0 + tt * 16 + q;
            const int tl   = trow & (TT - 1);
            if (mat == 2) {
                const int b = trow >> 11;
                #pragma unroll
                for (int r = 0; r < 4; ++r)
                    vt[((size_t)(b * HEADH) + hbase + r) * TT + tl] = f2bf(acc[j][tt][r]);
            } else {
                const float sc = (mat == 0) ? qscale : 1.f;
                unsigned short* dst = ((mat == 0) ? qo : ko) + (size_t)trow * HEADH;
                const int half = hbase >> 5;
                const float* frt = half ? fyr : fxr;
                const float* fit = half ? fyi : fxi;
                const int pi0 = (hbase & 31) >> 1;
                float fr0 = frt[tl * 16 + pi0],     fi0 = fit[tl * 16 + pi0];
                float fr1 = frt[tl * 16 + pi0 + 1], fi1 = fit[tl * 16 + pi0 + 1];
                float e0 = acc[j][tt][0] * fr0 - acc[j][tt][1] * fi0;
                float e1 = acc[j][tt][0] * fi0 + acc[j][tt][1] * fr0;
                float e2 = acc[j][tt][2] * fr1 - acc[j][tt][3] * fi1;
                float e3 = acc[j][tt][2] * fi1 + acc[j][tt][3] * fr1;
                uint2 ow;
                ow.x = packbf(e0 * sc, e1 * sc);
                ow.y = packbf(e2 * sc, e3 * sc);
                *(uint2*)(dst + hbase) = ow;
            }
        }
    }
#undef STAGE_X
}

// ---------------- Kernel B: MFMA flash attention, T4 counted-vmcnt ----------
// Round 21: r17's exact data path, but the per-iter __syncthreads (implicit
// vmcnt(0) drain on the just-issued stage) is replaced by the r20-VALIDATED
// T4 pattern: triple-buffered K/V staging, iter head = s_waitcnt vmcnt(2)
// (own buf-i calls complete; the 2 newer buf-i+1 calls stay in flight) +
// raw s_barrier, then stage buf (i+2)%3. Each buffer gets ~2 iterations of
// flight before use. Evidence attn is drain-sensitive: r9->r10's mid-iter
// vmcnt(0) cost +24us. Per-wave staging = exactly 2 calls/iter (1 K, 1 V)
// -> vmcnt arithmetic is exact (no other vmem in the loop).
// WAR safe: all LDS reads are MFMA-consumed (lgkm-complete) before each
// wave reaches the barrier; buf (i+2)%3 was last read in iter i-1, which
// all waves finished before passing the iter-i barrier.
// LDS 128KB: K[2h][3buf][8K] 48K | V same 48K | plds 32K. 1 block/CU
// (unchanged from r17's 96KB). Combine overlays the first 66KB.
__global__ __launch_bounds__(1024, 4) void attn_mfma_kernel(
    const unsigned short* __restrict__ qws,   // [b][t][64] bf16, pre-scaled
    const unsigned short* __restrict__ kws,   // [b][t][64] bf16
    const unsigned short* __restrict__ vtw,   // [b][d][t]  bf16 (V^T)
    float* __restrict__ out)
{
    __shared__ unsigned char smem[131072];

    const int tid = threadIdx.x;
    const int w   = tid >> 6;                 // 0..15
    const int wq  = w & 7;                    // q-subtile
    const int h   = w >> 3;                   // kv half
    const int l   = tid & 63;
    const int q   = l & 15;
    const int g   = l >> 4;
    const int b   = blockIdx.x >> 4;
    const int q0  = (blockIdx.x & 15) << 7;   // 128 q-rows per block
    const int qw  = q0 + 16 * wq;             // this wave's q base
    const int rx  = q & 7;                    // read-side swizzle
    const int swz = (q & 7) << 2;             // plds swizzle (verified r2-r20)

    const int rl = l >> 3;
    const int sl = (l & 7) ^ rl;              // involution pre-swizzle

    unsigned int* pldsw = (unsigned int*)(smem + 98304 + (w << 11));

    const unsigned short* kbase = kws + (size_t)b * TT * HEADH;
    const unsigned short* vbase = vtw + (size_t)b * HEADH * TT;

    const unsigned short* ksrc = kbase + (size_t)(h * 1024 + 8 * wq + rl) * HEADH + 8 * sl;
    const unsigned short* vsrc = vbase + (size_t)(8 * wq + rl) * TT + h * 1024 + 8 * sl;

#define STAGE_TILE(buf, kv)  do {                                             \
        unsigned char* kd = smem + h * 24576 + (buf) * 8192 + (wq << 10);     \
        async_copy16(kd, ksrc + (size_t)(kv) * HEADH);                        \
        unsigned char* vd = smem + 49152 + h * 24576 + (buf) * 8192 + (wq << 10); \
        async_copy16(vd, vsrc + (kv));                                        \
    } while (0)

    short8v qf0, qf1;
    {
        const unsigned short* qp = qws + ((size_t)(b * TT + qw + q)) * HEADH + 8 * g;
        qf0 = *(const short8v*)(qp);
        qf1 = *(const short8v*)(qp + 32);
    }

    f32x4 oacc[4];
    #pragma unroll
    for (int mt = 0; mt < 4; ++mt) oacc[mt] = (f32x4){0.f, 0.f, 0.f, 0.f};
    float m = -1e30f, lsum = 0.f;

    STAGE_TILE(0, 0);                         // prologue: 2 tiles in flight
    STAGE_TILE(1, 64);

    #pragma unroll
    for (int it = 0; it < 16; ++it) {
        // own buf-it calls complete; the 2 newer calls stay in flight
        if (it < 15) asm volatile("s_waitcnt vmcnt(2)" ::: "memory");
        else         asm volatile("s_waitcnt vmcnt(0)" ::: "memory");
        __builtin_amdgcn_s_barrier();         // raw: no full drain
        if (it + 2 < 16) STAGE_TILE((it + 2) % 3, (it + 2) << 6);

        const unsigned char* kb = smem + h * 24576 + (it % 3) * 8192;
        const unsigned char* vb = smem + 49152 + h * 24576 + (it % 3) * 8192;

        // ---- QK^T from LDS ----
        f32x4 sacc[4];
        #pragma unroll
        for (int n = 0; n < 4; ++n) {
            const int r = 16 * n + q;
            const short8v k0 = *(const short8v*)(kb + r * 128 + ((g ^ rx) << 4));
            const short8v k1 = *(const short8v*)(kb + r * 128 + (((4 + g) ^ rx) << 4));
            f32x4 z = (f32x4){0.f, 0.f, 0.f, 0.f};
            z = __builtin_amdgcn_mfma_f32_16x16x32_bf16(k0, qf0, z, 0, 0, 0);
            z = __builtin_amdgcn_mfma_f32_16x16x32_bf16(k1, qf1, z, 0, 0, 0);
            sacc[n] = z;
        }

        // ---- online softmax (lane owns q-row qw + (l&15)) ----
        float nx[4];
        #pragma unroll
        for (int n = 0; n < 4; ++n)
            nx[n] = fmaxf(fmaxf(sacc[n][0], sacc[n][1]),
                          fmaxf(sacc[n][2], sacc[n][3]));
        float cmax = fmaxf(fmaxf(nx[0], nx[1]), fmaxf(nx[2], nx[3]));
        cmax = fmaxf(cmax, __shfl_xor(cmax, 16));
        cmax = fmaxf(cmax, __shfl_xor(cmax, 32));
        const float mnew = fmaxf(m, cmax);

        float p[4][4];
        #pragma unroll
        for (int n = 0; n < 4; ++n) {
            #pragma unroll
            for (int r = 0; r < 4; ++r)
                p[n][r] = EXP2R(sacc[n][r] - mnew);   // raw v_exp_f32
            uint2 wv;
            wv.x = packbf(p[n][0], p[n][1]);
            wv.y = packbf(p[n][2], p[n][3]);
            *(uint2*)&pldsw[q * 32 + ((8 * n + 2 * g) ^ swz)] = wv;
        }

        const float sc = EXP2R(m - mnew);
        if (__any(cmax > m)) {
            #pragma unroll
            for (int mt = 0; mt < 4; ++mt)
                #pragma unroll
                for (int r = 0; r < 4; ++r) oacc[mt][r] *= sc;
        }

        // ---- PV: out^T += V^T . P^T ----
        #pragma unroll
        for (int s = 0; s < 2; ++s) {
            const short8v pb = *(const short8v*)&pldsw[q * 32 + ((16 * s + 4 * g) ^ swz)];
            #pragma unroll
            for (int mt = 0; mt < 4; ++mt) {
                const int d = 16 * mt + q;
                const short8v vfr = *(const short8v*)(vb + d * 128 + ((((s << 2) + g) ^ rx) << 4));
                oacc[mt] = __builtin_amdgcn_mfma_f32_16x16x32_bf16(vfr, pb, oacc[mt], 0, 0, 0);
            }
        }

        // ---- psum reduce off the critical path ----
        float psum = 0.f;
        #pragma unroll
        for (int n = 0; n < 4; ++n)
            #pragma unroll
            for (int r = 0; r < 4; ++r) psum += p[n][r];
        psum += __shfl_xor(psum, 16);
        psum += __shfl_xor(psum, 32);
        lsum = lsum * sc + psum;
        m = mnew;
    }

    // ---- 2-way combine of KV-half partials through LDS ----
    __syncthreads();                           // all loop LDS reads done
    float* o_f  = (float*)smem;                // [2][128][64] f32 = 64KB
    float* ml_f = (float*)(smem + 65536);      // [2][2][128]
    {
        const int prow = h * 128 + 16 * wq + q;
        #pragma unroll
        for (int mt = 0; mt < 4; ++mt)
            *(f32x4*)&o_f[prow * 64 + 16 * mt + 4 * g] = oacc[mt];
        if (g == 0) {
            ml_f[h * 256 + 16 * wq + q]       = m;
            ml_f[h * 256 + 128 + 16 * wq + q] = lsum;
        }
    }
    __syncthreads();

    const int cq = tid >> 3;                   // 0..127: q row
    const int ch = (tid & 7) << 3;             // 0..56: h group of 8
    const float m0 = ml_f[cq],       l0 = ml_f[128 + cq];
    const float m1 = ml_f[256 + cq], l1 = ml_f[384 + cq];
    const float M  = fmaxf(m0, m1);
    const float a0 = EXP2R(m0 - M), a1 = EXP2R(m1 - M);
    const float inv = 1.f / (a0 * l0 + a1 * l1);
    const float* o0 = &o_f[cq * 64 + ch];
    const float* o1 = &o_f[(128 + cq) * 64 + ch];
    float4 A0 = *(const float4*)(o0), B0 = *(const float4*)(o0 + 4);
    float4 A1 = *(const float4*)(o1), B1 = *(const float4*)(o1 + 4);
    float* op = out + ((size_t)(b * TT + q0 + cq)) * HEADH + ch;
    *(float4*)(op)     = make_float4((a0 * A0.x + a1 * A1.x) * inv,
                                     (a0 * A0.y + a1 * A1.y) * inv,
                                     (a0 * A0.z + a1 * A1.z) * inv,
                                     (a0 * A0.w + a1 * A1.w) * inv);
    *(float4*)(op + 4) = make_float4((a0 * B0.x + a1 * B1.x) * inv,
                                     (a0 * B0.y + a1 * B1.y) * inv,
                                     (a0 * B0.z + a1 * B1.z) * inv,
                                     (a0 * B0.w + a1 * B1.w) * inv);
#undef STAGE_TILE
}

extern "C" void kernel_launch(void* const* d_in, const int* in_sizes, int n_in,
                              void* d_out, int out_size, void* d_ws, size_t ws_size,
                              hipStream_t stream)
{
    const float* x   = (const float*)d_in[0];
    const float* Wq  = (const float*)d_in[1];
    const float* Wk  = (const float*)d_in[2];
    const float* Wv  = (const float*)d_in[3];
    const float* fxr = (const float*)d_in[4];
    const float* fxi = (const float*)d_in[5];
    const float* fyr = (const float*)d_in[6];
    const float* fyi = (const float*)d_in[7];
    float* out = (float*)d_out;

    unsigned short* qo = (unsigned short*)d_ws;                  // 4 MB
    unsigned short* ko = qo + (size_t)BB * TT * HEADH;           // 4 MB
    unsigned short* vt = ko + (size_t)BB * TT * HEADH;           // 4 MB
    unsigned short* wb = vt + (size_t)BB * TT * HEADH;           // 192 KB

    wcvt_kernel<<<48, 256, 0, stream>>>(Wq, Wk, Wv, wb);
    qkv_mfma_kernel<<<(BB * TT) / 64, 256, 0, stream>>>(x, wb, fxr, fxi, fyr, fyi,
                                                        qo, ko, vt);
    attn_mfma_kernel<<<BB * 16, 1024, 0, stream>>>(qo, ko, vt, out);
}